// Round 11
// baseline (275.953 us; speedup 1.0000x reference)
//
#include <hip/hip_runtime.h>
#include <hip/hip_bf16.h>
#include <stdint.h>

#define B_    4
#define S_    2048
#define DIN   4096
#define DOUT  4096
#define NNZ_  167772
#define M_    (B_*S_)   // 8192

typedef __attribute__((ext_vector_type(4))) float f32x4;
typedef __attribute__((ext_vector_type(8))) short s16x8;
typedef __attribute__((ext_vector_type(8))) unsigned short u16x8;

__device__ __forceinline__ unsigned short f2bf(float f) {
    unsigned int u = __float_as_uint(f);
    u += 0x7FFFu + ((u >> 16) & 1u);   // RNE; inputs finite, no NaN handling needed
    return (unsigned short)(u >> 16);
}

__device__ __forceinline__ float bf2f(unsigned short h) {
    return __uint_as_float(((unsigned int)h) << 16);
}

__device__ __forceinline__ void gload16(const void* g, void* l) {
    __builtin_amdgcn_global_load_lds(
        (const __attribute__((address_space(1))) unsigned int*)g,
        (__attribute__((address_space(3))) unsigned int*)l,
        16, 0, 0);
}

// ---- prep kernels (round-3 verified: no dense delta; bf16 CAS scatter) ----

__global__ void cvt_both_kernel(const float* __restrict__ W,
                                const float* __restrict__ x,
                                unsigned short* __restrict__ Wb,
                                unsigned short* __restrict__ xb,
                                int n8w, int n8x) {
    int i = blockIdx.x * blockDim.x + threadIdx.x;
    const float* src;
    unsigned short* dst;
    int j;
    if (i < n8w) { src = W; dst = Wb; j = i; }
    else         { src = x; dst = xb; j = i - n8w; if (j >= n8x) return; }
    const f32x4* s4 = reinterpret_cast<const f32x4*>(src);
    f32x4 a0 = s4[2*j], a1 = s4[2*j+1];
    u16x8 o;
    o[0]=f2bf(a0[0]); o[1]=f2bf(a0[1]); o[2]=f2bf(a0[2]); o[3]=f2bf(a0[3]);
    o[4]=f2bf(a1[0]); o[5]=f2bf(a1[1]); o[6]=f2bf(a1[2]); o[7]=f2bf(a1[3]);
    reinterpret_cast<u16x8*>(dst)[j] = o;
}

__global__ void scatter_bf16_kernel(const float* __restrict__ vals,
                                    const int* __restrict__ rows,
                                    const int* __restrict__ cols,
                                    unsigned short* __restrict__ Wb, int nnz) {
    int i = blockIdx.x * blockDim.x + threadIdx.x;
    if (i >= nnz) return;
    size_t cell = (size_t)rows[i] * DIN + cols[i];
    unsigned int* word = reinterpret_cast<unsigned int*>(Wb) + (cell >> 1);
    const bool hiHalf = (cell & 1) != 0;
    const float v = vals[i];
    unsigned int old = *word, assumed;
    do {
        assumed = old;
        unsigned short h = hiHalf ? (unsigned short)(assumed >> 16)
                                  : (unsigned short)(assumed & 0xFFFFu);
        unsigned short nh = f2bf(bf2f(h) + v);
        unsigned int nw = hiHalf ? ((assumed & 0x0000FFFFu) | ((unsigned int)nh << 16))
                                 : ((assumed & 0xFFFF0000u) | (unsigned int)nh);
        old = atomicCAS(word, assumed, nw);
    } while (old != assumed);
}

// ---- GEMM: C[m][o] = sum_k xb[m][k] * Wb[o][k] + bias[o] ----
// Round 11: R7 schedule (verified 227 us gemm) MINUS s_setprio — the one
// knob never isolated (T5 evidence: ~0 to negative on lockstep barrier
// structures like this one; all R1-R10 variants carried it uniformly).
// Pure deletion: no semantic/register/LDS change.
//
// 256x256 tile, BK=64, 8 waves (2Mx4N), 512 threads, 128 KiB LDS dbuf.
// Two COUNTED vmcnt(4) fences per tile; no drain-to-0 in the main loop;
// no young-load waits (every fence targets loads issued 3 phases ago).
//
// Phase products: S1 af0*bf0  S2 af1*bf0  S3 af1*bf1  S4 af0*bf1
// (ordered so each fragment's FIRST lgkm-consume precedes any write
//  to its LDS region by >=1 barrier).
//
// Per-tile (reads buf p = t&1; 4 barriers, 2 counted fences):
//  S1: BAR; MFMA af0*bf0
//  S2: BAR; MFMA af1*bf0; vmcnt(4)   [drains A(t+1), issued (t-1).S3 — 3
//                                     phases old; leaves B(t+1) in flight]
//  S3: BAR; MFMA af1*bf1; read af1(t+1)[8, buf 1-p]; stage A(t+2)->buf p;
//      vmcnt(4)                      [drains B(t+1), issued (t-1).S4 — 3
//                                     phases old; leaves A(t+2) in flight]
//  S4: BAR; MFMA af0*bf1; read af0(t+1)[8] + bf0(t+1)[4] + bf1(t+1)[4]
//      (buf 1-p); stage B(t+2)->buf p
//
// Hazard ledger:
//  * read af1(t+1) @ S3: A(t+1) drained by S2-end fence; S3's BAR makes it
//    cross-wave. SAFE.
//  * reads @ S4: A(t+1) drained S2-end; B(t+1) drained S3-end; S4's BAR
//    cross-wave. SAFE.
//  * stage A(t+2)->buf p.A @ S3: readers af0(t)/af1(t) lgkm-consumed by
//    t.S1/t.S2 MFMA heads; arrival at S3's BAR implies completion. SAFE.
//  * stage B(t+2)->buf p.B @ S4: readers bf0(t) [t.S1], bf1(t) [t.S3];
//    S4's BAR separates. SAFE.
//  * register WAR: within-wave program order (each frag overwritten only
//    after its last consuming MFMA in the same phase).
//  * fences wait only on loads issued 3 phases (~2000 cyc) earlier.
//
// Session record: R1 236 / R4 220(latent race) / R5 243 / R6 243 /
// R7 227 (race-free best) / R8 246 / R9 502(spill) / R10 227 (repro).
// Structural ceiling: acc(128)+frags(96)+addr ~= 256 unified = full
// register file at 2 waves/SIMD -> 1 block/CU; LDS pipe (2816 cyc/tile)
// ~ MFMA pipe (2483) near-parity; composite floor ~150 us gemm.

__global__ __launch_bounds__(512, 2) void gemm_kernel(
    const unsigned short* __restrict__ A,   // xb [M][K] bf16 bits
    const unsigned short* __restrict__ Bw,  // Wb [N][K] bf16 bits
    const float* __restrict__ bias,
    float* __restrict__ C)                  // [M][N] fp32
{
    constexpr int K  = DIN;    // 4096
    constexpr int N  = DOUT;   // 4096
    constexpr int KB = K * 2;  // 8192 bytes per row
    extern __shared__ char smem[];   // [2 bufs][A 32K | B 32K] = 128 KiB

    const int tid  = threadIdx.x;
    const int wave = tid >> 6;
    const int lane = tid & 63;
    const int wr = wave >> 2;          // 0..1  (M waves)
    const int wc = wave & 3;           // 0..3  (N waves)
    const int l16 = lane & 15;
    const int kq  = lane >> 4;         // 0..3
    const int s7  = l16 & 7;

    // XCD-aware bijective swizzle: 512 wgs, 8 XCDs -> 64 contiguous wgs/XCD.
    const int wg  = blockIdx.x;
    const int swz = (wg & 7) * 64 + (wg >> 3);
    const int bx  = swz & 15;          // N block 0..15
    const int by  = swz >> 4;          // M block 0..31
    const int rowBase = by * 256;
    const int colBase = bx * 256;

    // staging: per-thread global source, pre-swizzled (slot ^= row&7).
    // LDS dest stays linear: base + instr*8192 + wave*1024 (+ lane*16 impl.)
    const int r0    = tid >> 3;                   // row within 64-row chunk
    const int gslot = (tid & 7) ^ (r0 & 7);
    const char* gA = (const char*)A  + (size_t)(rowBase + r0) * KB + gslot * 16;
    const char* gB = (const char*)Bw + (size_t)(colBase + r0) * KB + gslot * 16;
    const int wvoff = wave * 1024;

    // LDS read pointers: row*128B + ((ks*4+kq)^s7)*16B, per buffer.
    const unsigned q0 = (unsigned)(kq ^ s7);        // ks=0 slot
    const unsigned q1 = (unsigned)((4 + kq) ^ s7);  // ks=1 slot
    const unsigned aBase = (unsigned)((wr * 128 + l16) * 128);
    const unsigned bBase = (unsigned)((wc * 64  + l16) * 128);
    const unsigned short* aPtr[2][2];
    const unsigned short* bPtr[2][2];
    #pragma unroll
    for (int p_ = 0; p_ < 2; ++p_) {
        aPtr[p_][0] = (const unsigned short*)(smem + p_ * 65536 + aBase + q0 * 16);
        aPtr[p_][1] = (const unsigned short*)(smem + p_ * 65536 + aBase + q1 * 16);
        bPtr[p_][0] = (const unsigned short*)(smem + p_ * 65536 + 32768 + bBase + q0 * 16);
        bPtr[p_][1] = (const unsigned short*)(smem + p_ * 65536 + 32768 + bBase + q1 * 16);
    }

    f32x4 acc[8][4];
    #pragma unroll
    for (int i = 0; i < 8; ++i)
        #pragma unroll
        for (int j = 0; j < 4; ++j) acc[i][j] = f32x4{0.f, 0.f, 0.f, 0.f};

    // persistent fragment registers (live across tiles)
    s16x8 af0[4][2], af1[4][2], bf0[2][2], bf1[2][2];

#define STAGE_A(P, T, H) do { \
    const char* g_ = gA + (size_t)(T) * 128 + (size_t)(H) * 1048576; \
    gload16(g_,          smem + (P) * 65536 + (H) * 16384 + wvoff); \
    gload16(g_ + 524288, smem + (P) * 65536 + (H) * 16384 + 8192 + wvoff); \
} while (0)

#define STAGE_B(P, T, H) do { \
    const char* g_ = gB + (size_t)(T) * 128 + (size_t)(H) * 1048576; \
    gload16(g_,          smem + (P) * 65536 + 32768 + (H) * 16384 + wvoff); \
    gload16(g_ + 524288, smem + (P) * 65536 + 32768 + (H) * 16384 + 8192 + wvoff); \
} while (0)

#define BAR() asm volatile("s_barrier" ::: "memory")

#define MFMA16(D, Af, Bf) D = __builtin_amdgcn_mfma_f32_16x16x32_bf16(Af, Bf, D, 0, 0, 0)

// TILE(P = buffer parity, T = tile, SS = stage t+2, RN = read t+1 frags,
//      F2 = S2-end fence (4 | -1), F3 = S3-end fence (4 | 0 | -1))
#define TILE(P, T, SS, RN, F2, F3) do { \
    /* ---- S1: af0*bf0 ---- */ \
    BAR(); \
    _Pragma("unroll") \
    for (int m_ = 0; m_ < 4; ++m_) \
      _Pragma("unroll") \
      for (int n_ = 0; n_ < 2; ++n_) { \
        MFMA16(acc[m_][n_], af0[m_][0], bf0[n_][0]); \
        MFMA16(acc[m_][n_], af0[m_][1], bf0[n_][1]); } \
    /* ---- S2: af1*bf0; counted fence (drain A(t+1)) ---- */ \
    BAR(); \
    _Pragma("unroll") \
    for (int m_ = 0; m_ < 4; ++m_) \
      _Pragma("unroll") \
      for (int n_ = 0; n_ < 2; ++n_) { \
        MFMA16(acc[4 + m_][n_], af1[m_][0], bf0[n_][0]); \
        MFMA16(acc[4 + m_][n_], af1[m_][1], bf0[n_][1]); } \
    if ((F2) == 4) { asm volatile("s_waitcnt vmcnt(4)" ::: "memory"); } \
    /* ---- S3: af1*bf1; read af1(t+1); stage A(t+2); fence (drain B(t+1)) */ \
    BAR(); \
    _Pragma("unroll") \
    for (int m_ = 0; m_ < 4; ++m_) \
      _Pragma("unroll") \
      for (int n_ = 0; n_ < 2; ++n_) { \
        MFMA16(acc[4 + m_][2 + n_], af1[m_][0], bf1[n_][0]); \
        MFMA16(acc[4 + m_][2 + n_], af1[m_][1], bf1[n_][1]); } \
    if (RN) { \
      _Pragma("unroll") \
      for (int m_ = 0; m_ < 4; ++m_) { \
        af1[m_][0] = *(const s16x8*)(aPtr[1 - (P)][0] + 4096 + m_ * 1024); \
        af1[m_][1] = *(const s16x8*)(aPtr[1 - (P)][1] + 4096 + m_ * 1024); } } \
    if (SS) { STAGE_A(P, (T) + 2, 0); STAGE_A(P, (T) + 2, 1); } \
    if ((F3) == 4)      { asm volatile("s_waitcnt vmcnt(4)" ::: "memory"); } \
    else if ((F3) == 0) { asm volatile("s_waitcnt vmcnt(0)" ::: "memory"); } \
    /* ---- S4: af0*bf1; read af0/bf0/bf1(t+1); stage B(t+2) ---- */ \
    BAR(); \
    _Pragma("unroll") \
    for (int m_ = 0; m_ < 4; ++m_) \
      _Pragma("unroll") \
      for (int n_ = 0; n_ < 2; ++n_) { \
        MFMA16(acc[m_][2 + n_], af0[m_][0], bf1[n_][0]); \
        MFMA16(acc[m_][2 + n_], af0[m_][1], bf1[n_][1]); } \
    if (RN) { \
      _Pragma("unroll") \
      for (int m_ = 0; m_ < 4; ++m_) { \
        af0[m_][0] = *(const s16x8*)(aPtr[1 - (P)][0] + m_ * 1024); \
        af0[m_][1] = *(const s16x8*)(aPtr[1 - (P)][1] + m_ * 1024); } \
      _Pragma("unroll") \
      for (int n_ = 0; n_ < 2; ++n_) { \
        bf0[n_][0] = *(const s16x8*)(bPtr[1 - (P)][0] + n_ * 1024); \
        bf0[n_][1] = *(const s16x8*)(bPtr[1 - (P)][1] + n_ * 1024); \
        bf1[n_][0] = *(const s16x8*)(bPtr[1 - (P)][0] + 2048 + n_ * 1024); \
        bf1[n_][1] = *(const s16x8*)(bPtr[1 - (P)][1] + 2048 + n_ * 1024); } } \
    if (SS) { STAGE_B(P, (T) + 2, 0); STAGE_B(P, (T) + 2, 1); } \
} while (0)

    // prologue: stage tile0 then tile1 (A before B in each, matching the
    // steady-state A-older-than-B queue order); drain tile0 (vmcnt(8)
    // keeps tile1's 8 in flight); pre-read ALL tile-0 fragments.
    STAGE_A(0, 0, 0); STAGE_A(0, 0, 1);
    STAGE_B(0, 0, 0); STAGE_B(0, 0, 1);
    STAGE_A(1, 1, 0); STAGE_A(1, 1, 1);
    STAGE_B(1, 1, 0); STAGE_B(1, 1, 1);
    asm volatile("s_waitcnt vmcnt(8)" ::: "memory");
    BAR();
    #pragma unroll
    for (int m_ = 0; m_ < 4; ++m_) {
        af0[m_][0] = *(const s16x8*)(aPtr[0][0] + m_ * 1024);
        af0[m_][1] = *(const s16x8*)(aPtr[0][1] + m_ * 1024);
        af1[m_][0] = *(const s16x8*)(aPtr[0][0] + 4096 + m_ * 1024);
        af1[m_][1] = *(const s16x8*)(aPtr[0][1] + 4096 + m_ * 1024);
    }
    #pragma unroll
    for (int n_ = 0; n_ < 2; ++n_) {
        bf0[n_][0] = *(const s16x8*)(bPtr[0][0] + n_ * 1024);
        bf0[n_][1] = *(const s16x8*)(bPtr[0][1] + n_ * 1024);
        bf1[n_][0] = *(const s16x8*)(bPtr[0][0] + 2048 + n_ * 1024);
        bf1[n_][1] = *(const s16x8*)(bPtr[0][1] + 2048 + n_ * 1024);
    }

    // main loop: tiles 0..61 full; 62 reads t+1 only (B(63) drains via
    // F3=0 — outstanding is only B(63), 3 phases old); 63 MFMA-only.
    #pragma unroll 1
    for (int t = 0; t < 62; t += 2) {
        TILE(0, t,     1, 1, 4, 4);
        TILE(1, t + 1, 1, 1, 4, 4);
    }
    TILE(0, 62, 0, 1, 4, 0);
    TILE(1, 63, 0, 0, -1, -1);

#undef TILE
#undef MFMA16
#undef BAR
#undef STAGE_A
#undef STAGE_B

    // epilogue: C/D layout col = lane&15, row = (lane>>4)*4 + j
    float bv[4];
    #pragma unroll
    for (int nf = 0; nf < 4; ++nf)
        bv[nf] = bias[colBase + wc * 64 + nf * 16 + l16];

    #pragma unroll
    for (int mf = 0; mf < 8; ++mf) {
        const int rowG = rowBase + wr * 128 + mf * 16 + kq * 4;
        float* cp = C + (size_t)rowG * N + colBase + wc * 64 + l16;
        #pragma unroll
        for (int nf = 0; nf < 4; ++nf)
            #pragma unroll
            for (int j = 0; j < 4; ++j)
                cp[(size_t)j * N + nf * 16] = acc[mf][nf][j] + bv[nf];
    }
}

extern "C" void kernel_launch(void* const* d_in, const int* in_sizes, int n_in,
                              void* d_out, int out_size, void* d_ws, size_t ws_size,
                              hipStream_t stream) {
    const float* x     = (const float*)d_in[0];
    const float* W     = (const float*)d_in[1];
    const float* b     = (const float*)d_in[2];
    const float* dvals = (const float*)d_in[3];
    const int*   drows = (const int*)d_in[4];
    const int*   dcols = (const int*)d_in[5];
    float* out = (float*)d_out;

    char* ws = (char*)d_ws;
    unsigned short* Wb = (unsigned short*)ws;                                   // 32 MiB
    unsigned short* xb = (unsigned short*)(ws + (size_t)32 * 1024 * 1024);      // 64 MiB

    // prep: one merged conversion pass (W->Wb, x->xb), then sparse
    // bf16 CAS-scatter of the corrections into Wb.
    int n8w = DOUT * DIN / 8;  // 2097152
    int n8x = M_ * DIN / 8;    // 4194304
    int nblk = (n8w + n8x) / 256;  // 24576
    cvt_both_kernel<<<nblk, 256, 0, stream>>>(W, x, Wb, xb, n8w, n8x);
    scatter_bf16_kernel<<<(NNZ_ + 255) / 256, 256, 0, stream>>>(dvals, drows, dcols, Wb, NNZ_);

    static bool attr_done = false;
    if (!attr_done) {
        (void)hipFuncSetAttribute(reinterpret_cast<const void*>(gemm_kernel),
                                  hipFuncAttributeMaxDynamicSharedMemorySize, 131072);
        attr_done = true;
    }
    // grid: 512 wgs (16 N-blocks x 32 M-blocks), 512 threads, 128 KiB LDS
    gemm_kernel<<<dim3(512), dim3(512), 131072, stream>>>(xb, Wb, b, out);
}

// Round 12
// 268.921 us; speedup vs baseline: 1.0261x; 1.0261x over previous
//
#include <hip/hip_runtime.h>
#include <hip/hip_bf16.h>
#include <stdint.h>

#define B_    4
#define S_    2048
#define DIN   4096
#define DOUT  4096
#define NNZ_  167772
#define M_    (B_*S_)   // 8192

typedef __attribute__((ext_vector_type(4))) float f32x4;
typedef __attribute__((ext_vector_type(8))) short s16x8;
typedef __attribute__((ext_vector_type(8))) unsigned short u16x8;

__device__ __forceinline__ unsigned short f2bf(float f) {
    unsigned int u = __float_as_uint(f);
    u += 0x7FFFu + ((u >> 16) & 1u);   // RNE; inputs finite, no NaN handling needed
    return (unsigned short)(u >> 16);
}

__device__ __forceinline__ float bf2f(unsigned short h) {
    return __uint_as_float(((unsigned int)h) << 16);
}

__device__ __forceinline__ void gload16(const void* g, void* l) {
    __builtin_amdgcn_global_load_lds(
        (const __attribute__((address_space(1))) unsigned int*)g,
        (__attribute__((address_space(3))) unsigned int*)l,
        16, 0, 0);
}

// ---- prep kernels (round-3 verified: no dense delta; bf16 CAS scatter) ----

__global__ void cvt_both_kernel(const float* __restrict__ W,
                                const float* __restrict__ x,
                                unsigned short* __restrict__ Wb,
                                unsigned short* __restrict__ xb,
                                int n8w, int n8x) {
    int i = blockIdx.x * blockDim.x + threadIdx.x;
    const float* src;
    unsigned short* dst;
    int j;
    if (i < n8w) { src = W; dst = Wb; j = i; }
    else         { src = x; dst = xb; j = i - n8w; if (j >= n8x) return; }
    const f32x4* s4 = reinterpret_cast<const f32x4*>(src);
    f32x4 a0 = s4[2*j], a1 = s4[2*j+1];
    u16x8 o;
    o[0]=f2bf(a0[0]); o[1]=f2bf(a0[1]); o[2]=f2bf(a0[2]); o[3]=f2bf(a0[3]);
    o[4]=f2bf(a1[0]); o[5]=f2bf(a1[1]); o[6]=f2bf(a1[2]); o[7]=f2bf(a1[3]);
    reinterpret_cast<u16x8*>(dst)[j] = o;
}

__global__ void scatter_bf16_kernel(const float* __restrict__ vals,
                                    const int* __restrict__ rows,
                                    const int* __restrict__ cols,
                                    unsigned short* __restrict__ Wb, int nnz) {
    int i = blockIdx.x * blockDim.x + threadIdx.x;
    if (i >= nnz) return;
    size_t cell = (size_t)rows[i] * DIN + cols[i];
    unsigned int* word = reinterpret_cast<unsigned int*>(Wb) + (cell >> 1);
    const bool hiHalf = (cell & 1) != 0;
    const float v = vals[i];
    unsigned int old = *word, assumed;
    do {
        assumed = old;
        unsigned short h = hiHalf ? (unsigned short)(assumed >> 16)
                                  : (unsigned short)(assumed & 0xFFFFu);
        unsigned short nh = f2bf(bf2f(h) + v);
        unsigned int nw = hiHalf ? ((assumed & 0x0000FFFFu) | ((unsigned int)nh << 16))
                                 : ((assumed & 0xFFFF0000u) | (unsigned int)nh);
        old = atomicCAS(word, assumed, nw);
    } while (old != assumed);
}

// ---- GEMM: C[m][o] = sum_k xb[m][k] * Wb[o][k] + bias[o] ----
// FINAL (R7/R10 schedule, verified twice: 227 us gemm, 268.7/269.9 us
// total, race-free; R11 A/B: setprio removal costs ~6 us -> kept):
// 256x256 tile, BK=64, 8 waves (2Mx4N), 512 threads, 128 KiB LDS dbuf.
// Two COUNTED vmcnt(4) fences per tile; no drain-to-0 in the main loop;
// no young-load waits (every fence targets loads issued 3 phases ago).
//
// Phase products: S1 af0*bf0  S2 af1*bf0  S3 af1*bf1  S4 af0*bf1
// (ordered so each fragment's FIRST lgkm-consume precedes any write
//  to its LDS region by >=1 barrier).
//
// Per-tile (reads buf p = t&1; 4 barriers, 2 counted fences):
//  S1: BAR; MFMA af0*bf0
//  S2: BAR; MFMA af1*bf0; vmcnt(4)   [drains A(t+1), issued (t-1).S3 — 3
//                                     phases old; leaves B(t+1) in flight]
//  S3: BAR; MFMA af1*bf1; read af1(t+1)[8, buf 1-p]; stage A(t+2)->buf p;
//      vmcnt(4)                      [drains B(t+1), issued (t-1).S4 — 3
//                                     phases old; leaves A(t+2) in flight]
//  S4: BAR; MFMA af0*bf1; read af0(t+1)[8] + bf0(t+1)[4] + bf1(t+1)[4]
//      (buf 1-p); stage B(t+2)->buf p
//
// Hazard ledger:
//  * read af1(t+1) @ S3: A(t+1) drained by S2-end fence; S3's BAR makes it
//    cross-wave (every wave ran its own fence before any crosses). SAFE.
//  * reads @ S4: A(t+1) drained S2-end; B(t+1) drained S3-end; S4's BAR
//    cross-wave. SAFE.
//  * stage A(t+2)->buf p.A @ S3: region readers af0(t) [read (t-1).S4,
//    lgkm-consumed at t.S1 MFMA head], af1(t) [read (t-1).S3, consumed at
//    t.S2 MFMA head]. Arrival at S3's BAR implies every wave completed S2
//    program order incl. those lgkm waits. SAFE.
//  * stage B(t+2)->buf p.B @ S4: readers bf0(t) [consumed t.S1], bf1(t)
//    [read (t-1).S4, consumed t.S3 MFMA head]; S4's BAR separates. SAFE.
//  * register WAR (within-wave program order): af1 used S2,S3, overwritten
//    S3 after MFMA; af0 used S1,S4, overwritten S4 after MFMA; bf0 used
//    S1,S2, overwritten S4; bf1 used S3,S4, overwritten S4 after MFMA.
//  * fences wait only on loads issued 3 phases (~2000 cyc) earlier ->
//    ~zero stall; staging loads always have a full tile in flight.
//
// Session record: R1 236 / R4 220(latent race) / R5 2-barrier+160KB 243 /
// R6 drain-0 243 / R7 THIS 227 / R8 8-phase 246 / R9 +16VGPR spill 502 /
// R10 repro 227 / R11 no-setprio 233. Structural ceiling: acc(128)+
// frags(96)+addr ~= 256 unified regs = full file at 2 waves/SIMD ->
// 1 block/CU, no co-residency; LDS pipe (~2816 cyc/tile incl. staged
// writes) ~ MFMA pipe (2483 cyc) near-parity; composite floor ~150 us.

__global__ __launch_bounds__(512, 2) void gemm_kernel(
    const unsigned short* __restrict__ A,   // xb [M][K] bf16 bits
    const unsigned short* __restrict__ Bw,  // Wb [N][K] bf16 bits
    const float* __restrict__ bias,
    float* __restrict__ C)                  // [M][N] fp32
{
    constexpr int K  = DIN;    // 4096
    constexpr int N  = DOUT;   // 4096
    constexpr int KB = K * 2;  // 8192 bytes per row
    extern __shared__ char smem[];   // [2 bufs][A 32K | B 32K] = 128 KiB

    const int tid  = threadIdx.x;
    const int wave = tid >> 6;
    const int lane = tid & 63;
    const int wr = wave >> 2;          // 0..1  (M waves)
    const int wc = wave & 3;           // 0..3  (N waves)
    const int l16 = lane & 15;
    const int kq  = lane >> 4;         // 0..3
    const int s7  = l16 & 7;

    // XCD-aware bijective swizzle: 512 wgs, 8 XCDs -> 64 contiguous wgs/XCD.
    const int wg  = blockIdx.x;
    const int swz = (wg & 7) * 64 + (wg >> 3);
    const int bx  = swz & 15;          // N block 0..15
    const int by  = swz >> 4;          // M block 0..31
    const int rowBase = by * 256;
    const int colBase = bx * 256;

    // staging: per-thread global source, pre-swizzled (slot ^= row&7).
    // LDS dest stays linear: base + instr*8192 + wave*1024 (+ lane*16 impl.)
    const int r0    = tid >> 3;                   // row within 64-row chunk
    const int gslot = (tid & 7) ^ (r0 & 7);
    const char* gA = (const char*)A  + (size_t)(rowBase + r0) * KB + gslot * 16;
    const char* gB = (const char*)Bw + (size_t)(colBase + r0) * KB + gslot * 16;
    const int wvoff = wave * 1024;

    // LDS read pointers: row*128B + ((ks*4+kq)^s7)*16B, per buffer.
    const unsigned q0 = (unsigned)(kq ^ s7);        // ks=0 slot
    const unsigned q1 = (unsigned)((4 + kq) ^ s7);  // ks=1 slot
    const unsigned aBase = (unsigned)((wr * 128 + l16) * 128);
    const unsigned bBase = (unsigned)((wc * 64  + l16) * 128);
    const unsigned short* aPtr[2][2];
    const unsigned short* bPtr[2][2];
    #pragma unroll
    for (int p_ = 0; p_ < 2; ++p_) {
        aPtr[p_][0] = (const unsigned short*)(smem + p_ * 65536 + aBase + q0 * 16);
        aPtr[p_][1] = (const unsigned short*)(smem + p_ * 65536 + aBase + q1 * 16);
        bPtr[p_][0] = (const unsigned short*)(smem + p_ * 65536 + 32768 + bBase + q0 * 16);
        bPtr[p_][1] = (const unsigned short*)(smem + p_ * 65536 + 32768 + bBase + q1 * 16);
    }

    f32x4 acc[8][4];
    #pragma unroll
    for (int i = 0; i < 8; ++i)
        #pragma unroll
        for (int j = 0; j < 4; ++j) acc[i][j] = f32x4{0.f, 0.f, 0.f, 0.f};

    // persistent fragment registers (live across tiles)
    s16x8 af0[4][2], af1[4][2], bf0[2][2], bf1[2][2];

#define STAGE_A(P, T, H) do { \
    const char* g_ = gA + (size_t)(T) * 128 + (size_t)(H) * 1048576; \
    gload16(g_,          smem + (P) * 65536 + (H) * 16384 + wvoff); \
    gload16(g_ + 524288, smem + (P) * 65536 + (H) * 16384 + 8192 + wvoff); \
} while (0)

#define STAGE_B(P, T, H) do { \
    const char* g_ = gB + (size_t)(T) * 128 + (size_t)(H) * 1048576; \
    gload16(g_,          smem + (P) * 65536 + 32768 + (H) * 16384 + wvoff); \
    gload16(g_ + 524288, smem + (P) * 65536 + 32768 + (H) * 16384 + 8192 + wvoff); \
} while (0)

#define BAR() asm volatile("s_barrier" ::: "memory")

#define MFMA16(D, Af, Bf) D = __builtin_amdgcn_mfma_f32_16x16x32_bf16(Af, Bf, D, 0, 0, 0)

// TILE(P = buffer parity, T = tile, SS = stage t+2, RN = read t+1 frags,
//      F2 = S2-end fence (4 | -1), F3 = S3-end fence (4 | 0 | -1))
#define TILE(P, T, SS, RN, F2, F3) do { \
    /* ---- S1: af0*bf0 ---- */ \
    BAR(); \
    __builtin_amdgcn_s_setprio(1); \
    _Pragma("unroll") \
    for (int m_ = 0; m_ < 4; ++m_) \
      _Pragma("unroll") \
      for (int n_ = 0; n_ < 2; ++n_) { \
        MFMA16(acc[m_][n_], af0[m_][0], bf0[n_][0]); \
        MFMA16(acc[m_][n_], af0[m_][1], bf0[n_][1]); } \
    __builtin_amdgcn_s_setprio(0); \
    /* ---- S2: af1*bf0; counted fence (drain A(t+1)) ---- */ \
    BAR(); \
    __builtin_amdgcn_s_setprio(1); \
    _Pragma("unroll") \
    for (int m_ = 0; m_ < 4; ++m_) \
      _Pragma("unroll") \
      for (int n_ = 0; n_ < 2; ++n_) { \
        MFMA16(acc[4 + m_][n_], af1[m_][0], bf0[n_][0]); \
        MFMA16(acc[4 + m_][n_], af1[m_][1], bf0[n_][1]); } \
    __builtin_amdgcn_s_setprio(0); \
    if ((F2) == 4) { asm volatile("s_waitcnt vmcnt(4)" ::: "memory"); } \
    /* ---- S3: af1*bf1; read af1(t+1); stage A(t+2); fence (drain B(t+1)) */ \
    BAR(); \
    __builtin_amdgcn_s_setprio(1); \
    _Pragma("unroll") \
    for (int m_ = 0; m_ < 4; ++m_) \
      _Pragma("unroll") \
      for (int n_ = 0; n_ < 2; ++n_) { \
        MFMA16(acc[4 + m_][2 + n_], af1[m_][0], bf1[n_][0]); \
        MFMA16(acc[4 + m_][2 + n_], af1[m_][1], bf1[n_][1]); } \
    __builtin_amdgcn_s_setprio(0); \
    if (RN) { \
      _Pragma("unroll") \
      for (int m_ = 0; m_ < 4; ++m_) { \
        af1[m_][0] = *(const s16x8*)(aPtr[1 - (P)][0] + 4096 + m_ * 1024); \
        af1[m_][1] = *(const s16x8*)(aPtr[1 - (P)][1] + 4096 + m_ * 1024); } } \
    if (SS) { STAGE_A(P, (T) + 2, 0); STAGE_A(P, (T) + 2, 1); } \
    if ((F3) == 4)      { asm volatile("s_waitcnt vmcnt(4)" ::: "memory"); } \
    else if ((F3) == 0) { asm volatile("s_waitcnt vmcnt(0)" ::: "memory"); } \
    /* ---- S4: af0*bf1; read af0/bf0/bf1(t+1); stage B(t+2) ---- */ \
    BAR(); \
    __builtin_amdgcn_s_setprio(1); \
    _Pragma("unroll") \
    for (int m_ = 0; m_ < 4; ++m_) \
      _Pragma("unroll") \
      for (int n_ = 0; n_ < 2; ++n_) { \
        MFMA16(acc[m_][2 + n_], af0[m_][0], bf1[n_][0]); \
        MFMA16(acc[m_][2 + n_], af0[m_][1], bf1[n_][1]); } \
    __builtin_amdgcn_s_setprio(0); \
    if (RN) { \
      _Pragma("unroll") \
      for (int m_ = 0; m_ < 4; ++m_) { \
        af0[m_][0] = *(const s16x8*)(aPtr[1 - (P)][0] + m_ * 1024); \
        af0[m_][1] = *(const s16x8*)(aPtr[1 - (P)][1] + m_ * 1024); } \
      _Pragma("unroll") \
      for (int n_ = 0; n_ < 2; ++n_) { \
        bf0[n_][0] = *(const s16x8*)(bPtr[1 - (P)][0] + n_ * 1024); \
        bf0[n_][1] = *(const s16x8*)(bPtr[1 - (P)][1] + n_ * 1024); \
        bf1[n_][0] = *(const s16x8*)(bPtr[1 - (P)][0] + 2048 + n_ * 1024); \
        bf1[n_][1] = *(const s16x8*)(bPtr[1 - (P)][1] + 2048 + n_ * 1024); } } \
    if (SS) { STAGE_B(P, (T) + 2, 0); STAGE_B(P, (T) + 2, 1); } \
} while (0)

    // prologue: stage tile0 then tile1 (A before B in each, matching the
    // steady-state A-older-than-B queue order); drain tile0 (vmcnt(8)
    // keeps tile1's 8 in flight); pre-read ALL tile-0 fragments.
    STAGE_A(0, 0, 0); STAGE_A(0, 0, 1);
    STAGE_B(0, 0, 0); STAGE_B(0, 0, 1);
    STAGE_A(1, 1, 0); STAGE_A(1, 1, 1);
    STAGE_B(1, 1, 0); STAGE_B(1, 1, 1);
    asm volatile("s_waitcnt vmcnt(8)" ::: "memory");
    BAR();
    #pragma unroll
    for (int m_ = 0; m_ < 4; ++m_) {
        af0[m_][0] = *(const s16x8*)(aPtr[0][0] + m_ * 1024);
        af0[m_][1] = *(const s16x8*)(aPtr[0][1] + m_ * 1024);
        af1[m_][0] = *(const s16x8*)(aPtr[0][0] + 4096 + m_ * 1024);
        af1[m_][1] = *(const s16x8*)(aPtr[0][1] + 4096 + m_ * 1024);
    }
    #pragma unroll
    for (int n_ = 0; n_ < 2; ++n_) {
        bf0[n_][0] = *(const s16x8*)(bPtr[0][0] + n_ * 1024);
        bf0[n_][1] = *(const s16x8*)(bPtr[0][1] + n_ * 1024);
        bf1[n_][0] = *(const s16x8*)(bPtr[0][0] + 2048 + n_ * 1024);
        bf1[n_][1] = *(const s16x8*)(bPtr[0][1] + 2048 + n_ * 1024);
    }

    // main loop: tiles 0..61 full; 62 reads t+1 only (B(63) drains via
    // F3=0 — outstanding is only B(63), 3 phases old); 63 MFMA-only.
    #pragma unroll 1
    for (int t = 0; t < 62; t += 2) {
        TILE(0, t,     1, 1, 4, 4);
        TILE(1, t + 1, 1, 1, 4, 4);
    }
    TILE(0, 62, 0, 1, 4, 0);
    TILE(1, 63, 0, 0, -1, -1);

#undef TILE
#undef MFMA16
#undef BAR
#undef STAGE_A
#undef STAGE_B

    // epilogue: C/D layout col = lane&15, row = (lane>>4)*4 + j
    float bv[4];
    #pragma unroll
    for (int nf = 0; nf < 4; ++nf)
        bv[nf] = bias[colBase + wc * 64 + nf * 16 + l16];

    #pragma unroll
    for (int mf = 0; mf < 8; ++mf) {
        const int rowG = rowBase + wr * 128 + mf * 16 + kq * 4;
        float* cp = C + (size_t)rowG * N + colBase + wc * 64 + l16;
        #pragma unroll
        for (int nf = 0; nf < 4; ++nf)
            #pragma unroll
            for (int j = 0; j < 4; ++j)
                cp[(size_t)j * N + nf * 16] = acc[mf][nf][j] + bv[nf];
    }
}

extern "C" void kernel_launch(void* const* d_in, const int* in_sizes, int n_in,
                              void* d_out, int out_size, void* d_ws, size_t ws_size,
                              hipStream_t stream) {
    const float* x     = (const float*)d_in[0];
    const float* W     = (const float*)d_in[1];
    const float* b     = (const float*)d_in[2];
    const float* dvals = (const float*)d_in[3];
    const int*   drows = (const int*)d_in[4];
    const int*   dcols = (const int*)d_in[5];
    float* out = (float*)d_out;

    char* ws = (char*)d_ws;
    unsigned short* Wb = (unsigned short*)ws;                                   // 32 MiB
    unsigned short* xb = (unsigned short*)(ws + (size_t)32 * 1024 * 1024);      // 64 MiB

    // prep: one merged conversion pass (W->Wb, x->xb), then sparse
    // bf16 CAS-scatter of the corrections into Wb.
    int n8w = DOUT * DIN / 8;  // 2097152
    int n8x = M_ * DIN / 8;    // 4194304
    int nblk = (n8w + n8x) / 256;  // 24576
    cvt_both_kernel<<<nblk, 256, 0, stream>>>(W, x, Wb, xb, n8w, n8x);
    scatter_bf16_kernel<<<(NNZ_ + 255) / 256, 256, 0, stream>>>(dvals, drows, dcols, Wb, NNZ_);

    static bool attr_done = false;
    if (!attr_done) {
        (void)hipFuncSetAttribute(reinterpret_cast<const void*>(gemm_kernel),
                                  hipFuncAttributeMaxDynamicSharedMemorySize, 131072);
        attr_done = true;
    }
    // grid: 512 wgs (16 N-blocks x 32 M-blocks), 512 threads, 128 KiB LDS
    gemm_kernel<<<dim3(512), dim3(512), 131072, stream>>>(xb, Wb, b, out);
}